// Round 1
// baseline (842.649 us; speedup 1.0000x reference)
//
#include <hip/hip_runtime.h>
#include <hip/hip_bf16.h>

#define NB 4096
#define NS 200
#define NE 64
#define NROWS (NB*NS)   // 819200

__device__ __forceinline__ float bf2f(unsigned v) {
    return __uint_as_float(v << 16);
}
__device__ __forceinline__ unsigned f2bf(float x) {
    unsigned u = __float_as_uint(x);
    u = u + 0x7fffu + ((u >> 16) & 1u);
    return u >> 16;
}
__device__ __forceinline__ float wsum(float v) {
    #pragma unroll
    for (int m = 32; m; m >>= 1) v += __shfl_xor(v, m, 64);
    return v;
}
__device__ __forceinline__ float wmax(float v) {
    #pragma unroll
    for (int m = 32; m; m >>= 1) v = fmaxf(v, __shfl_xor(v, m, 64));
    return v;
}

// ---------------- prep: zero stats accumulators, transpose W2 ----------------
__global__ __launch_bounds__(256) void k_prep(const float* __restrict__ W2,
                                              float* __restrict__ stats,
                                              float* __restrict__ W2T) {
    int t = threadIdx.x;
    if (t < 192) stats[t] = 0.f;
    #pragma unroll
    for (int r = 0; r < 8; ++r) {
        int idx = r*256 + t;
        int k = idx >> 5, j = idx & 31;
        W2T[j*64 + k] = W2[idx];
    }
}

// ---------------- pass1: h1 = folded(ai @ W1 + b1), col sums -----------------
// block = one batch b; 4 waves; lane j = output col; M[e] per-lane in VGPRs.
__global__ __launch_bounds__(256) void k_pass1(const float* __restrict__ query,
        const float* __restrict__ facts,
        const float* __restrict__ W1,
        const float* __restrict__ b1,
        float* __restrict__ gsum, float* __restrict__ gsq,
        unsigned* __restrict__ h1p) {
    __shared__ float qs[64];
    __shared__ float red[2][4][64];
    const int b = blockIdx.x;
    const int t = threadIdx.x;
    const int j = t & 63, w = t >> 6;
    if (t < 64) qs[t] = query[(size_t)b*64 + t];
    __syncthreads();
    float M[64];
    float qW = b1[j];
    const float* W1j = W1 + j;
    #pragma unroll
    for (int e = 0; e < 64; ++e) {
        float w0 = W1j[e*64];
        float w1 = W1j[(64+e)*64];
        float w2 = W1j[(128+e)*64];
        float w3 = W1j[(192+e)*64];
        float qe = qs[e];
        M[e] = (w1 - w2) + qe * w3;
        qW = fmaf(qe, w0 + w2, qW);
    }
    float sum = 0.f, ssq = 0.f;
    const float* fb = facts + (size_t)b * (NS*NE);
    unsigned* hrow = h1p + ((size_t)b*(NS/2))*64 + j;
    const int s0 = w * 50;
    for (int i = 0; i < 50; i += 2) {
        const int su = __builtin_amdgcn_readfirstlane(s0 + i);
        const float* f0 = fb + su*64;   // wave-uniform -> scalar loads
        float h0 = qW, h1 = qW;
        #pragma unroll
        for (int e = 0; e < 64; ++e) {
            h0 = fmaf(f0[e],    M[e], h0);
            h1 = fmaf(f0[64+e], M[e], h1);
        }
        sum += h0 + h1;
        ssq = fmaf(h0, h0, ssq);
        ssq = fmaf(h1, h1, ssq);
        hrow[(size_t)(su >> 1)*64] = f2bf(h0) | (f2bf(h1) << 16);
    }
    red[0][w][j] = sum;
    red[1][w][j] = ssq;
    __syncthreads();
    if (t < 64) {
        float a = red[0][0][t]+red[0][1][t]+red[0][2][t]+red[0][3][t];
        float c = red[1][0][t]+red[1][1][t]+red[1][2][t]+red[1][3][t];
        atomicAdd(gsum + t, a);
        atomicAdd(gsq + t, c);
    }
}

// -------- finalize: fold BN+Dice into 4 per-channel constants A,B,G,H --------
// bn(h)=A*h+B ; gate_in=G*h+H (dice inner-BN stats derived analytically)
__global__ __launch_bounds__(64) void k_fin(const float* __restrict__ gsum,
        const float* __restrict__ gsq,
        const float* __restrict__ gam, const float* __restrict__ bet,
        const float* __restrict__ dg, const float* __restrict__ db,
        float* __restrict__ C, int n) {
    int j = threadIdx.x;
    if (j >= n) return;
    const float Ninv = 1.0f / (float)NROWS;
    float m = gsum[j] * Ninv;
    float v = fmaxf(gsq[j]*Ninv - m*m, 0.f);
    float rstd = rsqrtf(v + 1e-5f);
    float A = gam[j] * rstd;
    float Bc = bet[j] - A*m;
    float vard = A*A*v;                   // = gamma^2 * v/(v+eps)
    float rstdd = rsqrtf(vard + 1e-8f);
    float G = dg[j] * rstdd * A;
    float H = db[j] - G*m;
    C[j] = A; C[n+j] = Bc; C[2*n+j] = G; C[3*n+j] = H;
}

// --------- pass2: h1 -> dice1 -> h2 = h1d @ W2 + b2 (bf16 out) ---------------
__global__ __launch_bounds__(256) void k_pass2(const unsigned* __restrict__ h1p,
        const float* __restrict__ C1, const float* __restrict__ a1,
        const float* __restrict__ W2T, const float* __restrict__ b2,
        unsigned* __restrict__ h2p) {
    const int t = threadIdx.x;
    const size_t g = (size_t)blockIdx.x * 256 + t;
    const uint4* rv = (const uint4*)(h1p + (g >> 1) * 64);
    const bool odd = (g & 1);
    float hd[64];
    #pragma unroll
    for (int kk = 0; kk < 16; ++kk) {
        uint4 u = rv[kk];
        unsigned uu[4] = {u.x, u.y, u.z, u.w};
        #pragma unroll
        for (int q = 0; q < 4; ++q) {
            int k = kk*4 + q;
            unsigned bits = odd ? (uu[q] & 0xffff0000u) : (uu[q] << 16);
            float h = __uint_as_float(bits);
            float x  = fmaf(C1[k],     h, C1[64+k]);
            float tg = fmaf(C1[128+k], h, C1[192+k]);
            float gate = __builtin_amdgcn_rcpf(1.f + __expf(-tg));
            float al = a1[k];
            hd[k] = x * fmaf(gate, 1.f - al, al);
        }
    }
    unsigned* orow = h2p + g*16;
    for (int jp = 0; jp < 16; ++jp) {
        float ac0 = b2[2*jp], ac1 = b2[2*jp+1];
        const float* w0 = W2T + (2*jp)*64;
        const float* w1 = W2T + (2*jp+1)*64;
        #pragma unroll
        for (int k = 0; k < 64; ++k) {
            ac0 = fmaf(hd[k], w0[k], ac0);
            ac1 = fmaf(hd[k], w1[k], ac1);
        }
        orow[jp] = f2bf(ac0) | (f2bf(ac1) << 16);
    }
}

// ---------------- stats2: column sums of h2 (reads bf16 pairs) ---------------
__global__ __launch_bounds__(256) void k_stats2(const unsigned* __restrict__ h2p,
        float* __restrict__ gsum2, float* __restrict__ gsq2) {
    const int t = threadIdx.x;
    float slo=0, qlo=0, shi=0, qhi=0;
    size_t base = (size_t)blockIdx.x * 256 + t;
    #pragma unroll 5
    for (int it = 0; it < 25; ++it) {
        unsigned u = h2p[base + (size_t)it * (2048u*256u)];
        float lo = bf2f(u & 0xffffu);
        float hi = bf2f(u >> 16);
        slo += lo; qlo = fmaf(lo, lo, qlo);
        shi += hi; qhi = fmaf(hi, hi, qhi);
    }
    __shared__ float red[256][4];
    red[t][0]=slo; red[t][1]=qlo; red[t][2]=shi; red[t][3]=qhi;
    __syncthreads();
    if (t < 64) {
        int cc = t & 15, which = t >> 4;
        float v = 0;
        #pragma unroll
        for (int k = 0; k < 16; ++k) v += red[cc + 16*k][which];
        int col = 2*cc + (which >> 1);
        float* dst = (which & 1) ? gsq2 : gsum2;
        atomicAdd(dst + col, v);
    }
}

// ------- pass3: dice2 + scores + mask + softmax + weighted facts sum ---------
__global__ __launch_bounds__(256) void k_pass3(const unsigned* __restrict__ h2p,
        const float* __restrict__ C2, const float* __restrict__ a2,
        const float* __restrict__ Wf, const float* __restrict__ bfp,
        const int* __restrict__ mask, const float* __restrict__ facts,
        float* __restrict__ out) {
    __shared__ float rmax[4], rsum[4], wgt[256], par[4][64];
    const int b = blockIdx.x, t = threadIdx.x;
    float score = -1e30f;
    if (t < NS) {
        size_t g = (size_t)b*NS + t;
        const uint4* hv = (const uint4*)(h2p + g*16);
        uint4 U0 = hv[0], U1 = hv[1], U2 = hv[2], U3 = hv[3];
        unsigned uw[16] = {U0.x,U0.y,U0.z,U0.w, U1.x,U1.y,U1.z,U1.w,
                           U2.x,U2.y,U2.z,U2.w, U3.x,U3.y,U3.z,U3.w};
        float acc = bfp[0];
        #pragma unroll
        for (int jp = 0; jp < 16; ++jp) {
            unsigned u = uw[jp];
            #pragma unroll
            for (int h = 0; h < 2; ++h) {
                int k = 2*jp + h;
                float hval = bf2f(h ? (u >> 16) : (u & 0xffffu));
                float x  = fmaf(C2[k],    hval, C2[32+k]);
                float tg = fmaf(C2[64+k], hval, C2[96+k]);
                float gate = __builtin_amdgcn_rcpf(1.f + __expf(-tg));
                float al = a2[k];
                acc = fmaf(x * fmaf(gate, 1.f - al, al), Wf[k], acc);
            }
        }
        score = (mask[g] > 0) ? acc : -1e9f;
    }
    float m = wmax(score);
    if ((t & 63) == 0) rmax[t >> 6] = m;
    __syncthreads();
    m = fmaxf(fmaxf(rmax[0],rmax[1]), fmaxf(rmax[2],rmax[3]));
    float ee = __expf(score - m);
    float zs = wsum(ee);
    if ((t & 63) == 0) rsum[t >> 6] = zs;
    __syncthreads();
    float Z = rsum[0]+rsum[1]+rsum[2]+rsum[3];
    wgt[t] = ee * __builtin_amdgcn_rcpf(Z);
    __syncthreads();
    const int e = t & 63, p = t >> 6;
    const float* fb = facts + (size_t)b*(NS*NE) + e;
    float acc2 = 0.f;
    for (int s = p; s < NS; s += 4) {
        acc2 = fmaf(wgt[s], fb[(size_t)s*64], acc2);
    }
    par[p][e] = acc2;
    __syncthreads();
    if (t < 64) out[(size_t)b*64 + t] = par[0][t]+par[1][t]+par[2][t]+par[3][t];
}

extern "C" void kernel_launch(void* const* d_in, const int* in_sizes, int n_in,
                              void* d_out, int out_size, void* d_ws, size_t ws_size,
                              hipStream_t stream) {
    const float* query = (const float*)d_in[0];
    const float* facts = (const float*)d_in[1];
    const int*   mask  = (const int*)d_in[2];
    const float* W1  = (const float*)d_in[3];
    const float* b1  = (const float*)d_in[4];
    const float* g1  = (const float*)d_in[5];
    const float* be1 = (const float*)d_in[6];
    const float* dg1 = (const float*)d_in[7];
    const float* db1 = (const float*)d_in[8];
    const float* a1  = (const float*)d_in[9];
    const float* W2  = (const float*)d_in[10];
    const float* b2  = (const float*)d_in[11];
    const float* g2  = (const float*)d_in[12];
    const float* be2 = (const float*)d_in[13];
    const float* dg2 = (const float*)d_in[14];
    const float* db2 = (const float*)d_in[15];
    const float* a2  = (const float*)d_in[16];
    const float* Wf  = (const float*)d_in[17];
    const float* bff = (const float*)d_in[18];
    float* out = (float*)d_out;

    float* ws = (float*)d_ws;
    float* gsum1 = ws + 0;     // 64
    float* gsq1  = ws + 64;    // 64
    float* gsum2 = ws + 128;   // 32
    float* gsq2  = ws + 160;   // 32
    float* C1    = ws + 256;   // 256 (A,B,G,H x64)
    float* C2    = ws + 512;   // 128 (A,B,G,H x32)
    float* W2T   = ws + 640;   // 2048
    unsigned* h1p = (unsigned*)(ws + 4096);          // NROWS/2 * 64 u32 = 100 MB
    unsigned* h2p = h1p + (size_t)(NROWS/2)*64;      // NROWS * 16 u32 = 50 MB
    // total ws needed ~157.3 MB
    (void)ws_size; (void)in_sizes; (void)n_in; (void)out_size;

    k_prep<<<1, 256, 0, stream>>>(W2, ws, W2T);
    k_pass1<<<NB, 256, 0, stream>>>(query, facts, W1, b1, gsum1, gsq1, h1p);
    k_fin<<<1, 64, 0, stream>>>(gsum1, gsq1, g1, be1, dg1, db1, C1, 64);
    k_pass2<<<NROWS/256, 256, 0, stream>>>(h1p, C1, a1, W2T, b2, h2p);
    k_stats2<<<2048, 256, 0, stream>>>(h2p, gsum2, gsq2);
    k_fin<<<1, 32, 0, stream>>>(gsum2, gsq2, g2, be2, dg2, db2, C2, 32);
    k_pass3<<<NB, 256, 0, stream>>>(h2p, C2, a2, Wf, bff, mask, facts, out);
}

// Round 2
// 428.739 us; speedup vs baseline: 1.9654x; 1.9654x over previous
//
#include <hip/hip_runtime.h>
#include <hip/hip_bf16.h>

#define NB 4096
#define NS 200
#define NE 64
#define NROWS (NB*NS)   // 819200

typedef __attribute__((ext_vector_type(8))) short bf16x8;
typedef __attribute__((ext_vector_type(4))) float f32x4;

__device__ __forceinline__ float bf2f(unsigned v) {
    return __uint_as_float(v << 16);
}
__device__ __forceinline__ unsigned f2bf(float x) {
    unsigned u = __float_as_uint(x);
    u = u + 0x7fffu + ((u >> 16) & 1u);
    return u >> 16;
}
__device__ __forceinline__ float wsum(float v) {
    #pragma unroll
    for (int m = 32; m; m >>= 1) v += __shfl_xor(v, m, 64);
    return v;
}
__device__ __forceinline__ float wmax(float v) {
    #pragma unroll
    for (int m = 32; m; m >>= 1) v = fmaxf(v, __shfl_xor(v, m, 64));
    return v;
}

// ---------------- prep: zero stats accumulators, transpose W2 ----------------
__global__ __launch_bounds__(256) void k_prep(const float* __restrict__ W2,
                                              float* __restrict__ stats,
                                              float* __restrict__ W2T) {
    int t = threadIdx.x;
    if (t < 192) stats[t] = 0.f;
    #pragma unroll
    for (int r = 0; r < 8; ++r) {
        int idx = r*256 + t;
        int k = idx >> 5, j = idx & 31;
        W2T[j*64 + k] = W2[idx];
    }
}

// ---------------- pass1 (MFMA): h1 = facts @ M[b] + qW[b], col stats ---------
// block = one batch b; 4 waves. M[b][e][j] = (W1[64+e][j]-W1[128+e][j]) + q[e]*W1[192+e][j]
// qW[b][j] = b1[j] + sum_e q[e]*(W1[e][j]+W1[128+e][j])
__global__ __launch_bounds__(256) void k_pass1(const float* __restrict__ query,
        const float* __restrict__ facts,
        const float* __restrict__ W1,
        const float* __restrict__ b1,
        float* __restrict__ gsum, float* __restrict__ gsq,
        unsigned* __restrict__ h1p) {
    __shared__ float qs[64];
    __shared__ float red[4][64];
    __shared__ float qw[64];
    __shared__ unsigned Mt[64*36];     // Mt[j]: 32 data words (64 bf16, e-major) + 4 pad
    __shared__ unsigned h1s[208*32];   // [row][word], word bank-swizzled by ((row>>2)&3)<<3
    __shared__ float sred[4][128];

    const int b = blockIdx.x;
    const int t = threadIdx.x;
    const int l = t & 63, w = t >> 6;

    if (t < 64) qs[t] = query[(size_t)b*64 + t];
    __syncthreads();

    // ---- build M (bf16, transposed: Mt[j][e]) + qW partials ----
    {
        const int j = t & 63;
        const int e0 = (t >> 6) * 16;
        float qp = 0.f;
        #pragma unroll
        for (int ee = 0; ee < 16; ee += 2) {
            const int e = e0 + ee;
            float w0a = W1[(size_t)(e)*64 + j];
            float w1a = W1[(size_t)(64+e)*64 + j];
            float w2a = W1[(size_t)(128+e)*64 + j];
            float w3a = W1[(size_t)(192+e)*64 + j];
            float qe0 = qs[e];
            float m0 = (w1a - w2a) + qe0 * w3a;
            qp = fmaf(qe0, w0a + w2a, qp);
            float w0b = W1[(size_t)(e+1)*64 + j];
            float w1b = W1[(size_t)(64+e+1)*64 + j];
            float w2b = W1[(size_t)(128+e+1)*64 + j];
            float w3b = W1[(size_t)(192+e+1)*64 + j];
            float qe1 = qs[e+1];
            float m1 = (w1b - w2b) + qe1 * w3b;
            qp = fmaf(qe1, w0b + w2b, qp);
            Mt[j*36 + ((e0+ee)>>1)] = f2bf(m0) | (f2bf(m1) << 16);
        }
        red[t>>6][j] = qp;
    }
    __syncthreads();
    if (t < 64) qw[t] = b1[t] + red[0][t]+red[1][t]+red[2][t]+red[3][t];
    __syncthreads();

    // ---- B fragments: Bf[colgroup][kstep], lane: col=l&15, k=ks*32+8*(l>>4)+i ----
    bf16x8 Bf[4][2];
    #pragma unroll
    for (int cg = 0; cg < 4; ++cg) {
        #pragma unroll
        for (int ks = 0; ks < 2; ++ks) {
            int j = cg*16 + (l & 15);
            int e0 = ks*32 + 8*(l >> 4);
            Bf[cg][ks] = *(const bf16x8*)&Mt[j*36 + (e0 >> 1)];
        }
    }
    float qwr[4];
    #pragma unroll
    for (int cg = 0; cg < 4; ++cg) qwr[cg] = qw[cg*16 + (l & 15)];

    float s_acc[4] = {0,0,0,0}, q_acc[4] = {0,0,0,0};
    const float* fb = facts + (size_t)b*(NS*NE);

    for (int rt = w; rt < 13; rt += 4) {
        const int row = rt*16 + (l & 15);
        const int k0 = 8 * (l >> 4);
        float a0[8] = {0,0,0,0,0,0,0,0};
        float a1[8] = {0,0,0,0,0,0,0,0};
        if (row < 200) {
            const float* p = fb + (size_t)row*64 + k0;
            *(float4*)&a0[0] = *(const float4*)(p);
            *(float4*)&a0[4] = *(const float4*)(p + 4);
            *(float4*)&a1[0] = *(const float4*)(p + 32);
            *(float4*)&a1[4] = *(const float4*)(p + 36);
        }
        // split each float into hi(bf16) + lo(bf16 of residual)
        bf16x8 Ah0, Al0, Ah1, Al1;
        #pragma unroll
        for (int i = 0; i < 8; ++i) {
            unsigned hb = f2bf(a0[i]);
            Ah0[i] = (short)hb;
            Al0[i] = (short)f2bf(a0[i] - bf2f(hb));
            unsigned hb1 = f2bf(a1[i]);
            Ah1[i] = (short)hb1;
            Al1[i] = (short)f2bf(a1[i] - bf2f(hb1));
        }
        f32x4 cacc[4];
        #pragma unroll
        for (int cg = 0; cg < 4; ++cg) cacc[cg] = (f32x4){0.f,0.f,0.f,0.f};
        #pragma unroll
        for (int cg = 0; cg < 4; ++cg) {
            cacc[cg] = __builtin_amdgcn_mfma_f32_16x16x32_bf16(Ah0, Bf[cg][0], cacc[cg], 0,0,0);
            cacc[cg] = __builtin_amdgcn_mfma_f32_16x16x32_bf16(Ah1, Bf[cg][1], cacc[cg], 0,0,0);
            cacc[cg] = __builtin_amdgcn_mfma_f32_16x16x32_bf16(Al0, Bf[cg][0], cacc[cg], 0,0,0);
            cacc[cg] = __builtin_amdgcn_mfma_f32_16x16x32_bf16(Al1, Bf[cg][1], cacc[cg], 0,0,0);
        }
        // epilogue: +qW, stats, LDS h1 write. C layout: col=l&15(+16cg), row=4*(l>>4)+reg
        #pragma unroll
        for (int cg = 0; cg < 4; ++cg) {
            const int c_col = cg*16 + (l & 15);
            #pragma unroll
            for (int r = 0; r < 4; ++r) {
                const int rr = rt*16 + 4*(l >> 4) + r;
                float v = cacc[cg][r] + qwr[cg];
                if (rr < 200) {
                    s_acc[cg] += v;
                    q_acc[cg] = fmaf(v, v, q_acc[cg]);
                    const int g_ = (rr >> 2) & 3;
                    const int wrd = (c_col >> 1) ^ (g_ << 3);
                    ((unsigned short*)h1s)[rr*64 + wrd*2 + (c_col & 1)] =
                        (unsigned short)f2bf(v);
                }
            }
        }
    }

    // wave-level column reduce (combine the 4 lane-groups), stage to LDS
    #pragma unroll
    for (int cg = 0; cg < 4; ++cg) {
        s_acc[cg] += __shfl_xor(s_acc[cg], 16, 64);
        s_acc[cg] += __shfl_xor(s_acc[cg], 32, 64);
        q_acc[cg] += __shfl_xor(q_acc[cg], 16, 64);
        q_acc[cg] += __shfl_xor(q_acc[cg], 32, 64);
    }
    if ((l >> 4) == 0) {
        #pragma unroll
        for (int cg = 0; cg < 4; ++cg) {
            sred[w][cg*16 + l] = s_acc[cg];
            sred[w][64 + cg*16 + l] = q_acc[cg];
        }
    }
    __syncthreads();

    if (t < 128) {
        float v = sred[0][t]+sred[1][t]+sred[2][t]+sred[3][t];
        if (t < 64) atomicAdd(gsum + t, v);
        else        atomicAdd(gsq + (t - 64), v);
    }

    // coalesced h1 store: [row][32 words], unswizzle
    #pragma unroll
    for (int it = 0; it < 25; ++it) {
        const int idx = it*256 + t;
        const int row = idx >> 5, wd = idx & 31;
        const int sw = ((row >> 2) & 3) << 3;
        h1p[((size_t)b*200 + row)*32 + wd] = h1s[row*32 + (wd ^ sw)];
    }
}

// -------- finalize: fold BN+Dice into 4 per-channel constants A,B,G,H --------
__global__ __launch_bounds__(64) void k_fin(const float* __restrict__ gsum,
        const float* __restrict__ gsq,
        const float* __restrict__ gam, const float* __restrict__ bet,
        const float* __restrict__ dg, const float* __restrict__ db,
        float* __restrict__ C, int n) {
    int j = threadIdx.x;
    if (j >= n) return;
    const float Ninv = 1.0f / (float)NROWS;
    float m = gsum[j] * Ninv;
    float v = fmaxf(gsq[j]*Ninv - m*m, 0.f);
    float rstd = rsqrtf(v + 1e-5f);
    float A = gam[j] * rstd;
    float Bc = bet[j] - A*m;
    float vard = A*A*v;                   // = gamma^2 * v/(v+eps)
    float rstdd = rsqrtf(vard + 1e-8f);
    float G = dg[j] * rstdd * A;
    float H = db[j] - G*m;
    C[j] = A; C[n+j] = Bc; C[2*n+j] = G; C[3*n+j] = H;
}

// --------- pass2: h1 -> dice1 -> h2 = h1d @ W2 + b2 (bf16 out) ---------------
__global__ __launch_bounds__(256) void k_pass2(const unsigned* __restrict__ h1p,
        const float* __restrict__ C1, const float* __restrict__ a1,
        const float* __restrict__ W2T, const float* __restrict__ b2,
        unsigned* __restrict__ h2p) {
    const int t = threadIdx.x;
    const size_t g = (size_t)blockIdx.x * 256 + t;
    const uint4* rv = (const uint4*)(h1p + g*32);
    float hd[64];
    #pragma unroll
    for (int kk = 0; kk < 8; ++kk) {
        uint4 u = rv[kk];
        unsigned uu[4] = {u.x, u.y, u.z, u.w};
        #pragma unroll
        for (int q = 0; q < 4; ++q) {
            const int k = kk*8 + q*2;
            #pragma unroll
            for (int h = 0; h < 2; ++h) {
                const int kc = k + h;
                float hv = bf2f(h ? (uu[q] >> 16) : (uu[q] & 0xffffu));
                float x  = fmaf(C1[kc],     hv, C1[64+kc]);
                float tg = fmaf(C1[128+kc], hv, C1[192+kc]);
                float gate = __builtin_amdgcn_rcpf(1.f + __expf(-tg));
                float al = a1[kc];
                hd[kc] = x * fmaf(gate, 1.f - al, al);
            }
        }
    }
    unsigned* orow = h2p + g*16;
    for (int jp = 0; jp < 16; ++jp) {
        float ac0 = b2[2*jp], ac1 = b2[2*jp+1];
        const float* w0 = W2T + (2*jp)*64;
        const float* w1 = W2T + (2*jp+1)*64;
        #pragma unroll
        for (int k = 0; k < 64; ++k) {
            ac0 = fmaf(hd[k], w0[k], ac0);
            ac1 = fmaf(hd[k], w1[k], ac1);
        }
        orow[jp] = f2bf(ac0) | (f2bf(ac1) << 16);
    }
}

// ---------------- stats2: column sums of h2 (reads bf16 pairs) ---------------
__global__ __launch_bounds__(256) void k_stats2(const unsigned* __restrict__ h2p,
        float* __restrict__ gsum2, float* __restrict__ gsq2) {
    const int t = threadIdx.x;
    float slo=0, qlo=0, shi=0, qhi=0;
    size_t base = (size_t)blockIdx.x * 256 + t;
    #pragma unroll 5
    for (int it = 0; it < 25; ++it) {
        unsigned u = h2p[base + (size_t)it * (2048u*256u)];
        float lo = bf2f(u & 0xffffu);
        float hi = bf2f(u >> 16);
        slo += lo; qlo = fmaf(lo, lo, qlo);
        shi += hi; qhi = fmaf(hi, hi, qhi);
    }
    __shared__ float red[256][4];
    red[t][0]=slo; red[t][1]=qlo; red[t][2]=shi; red[t][3]=qhi;
    __syncthreads();
    if (t < 64) {
        int cc = t & 15, which = t >> 4;
        float v = 0;
        #pragma unroll
        for (int k = 0; k < 16; ++k) v += red[cc + 16*k][which];
        int col = 2*cc + (which >> 1);
        float* dst = (which & 1) ? gsq2 : gsum2;
        atomicAdd(dst + col, v);
    }
}

// ------- pass3: dice2 + scores + mask + softmax + weighted facts sum ---------
__global__ __launch_bounds__(256) void k_pass3(const unsigned* __restrict__ h2p,
        const float* __restrict__ C2, const float* __restrict__ a2,
        const float* __restrict__ Wf, const float* __restrict__ bfp,
        const int* __restrict__ mask, const float* __restrict__ facts,
        float* __restrict__ out) {
    __shared__ float rmax[4], rsum[4], wgt[256], par[4][64];
    const int b = blockIdx.x, t = threadIdx.x;
    float score = -1e30f;
    if (t < NS) {
        size_t g = (size_t)b*NS + t;
        const uint4* hv = (const uint4*)(h2p + g*16);
        uint4 U0 = hv[0], U1 = hv[1], U2 = hv[2], U3 = hv[3];
        unsigned uw[16] = {U0.x,U0.y,U0.z,U0.w, U1.x,U1.y,U1.z,U1.w,
                           U2.x,U2.y,U2.z,U2.w, U3.x,U3.y,U3.z,U3.w};
        float acc = bfp[0];
        #pragma unroll
        for (int jp = 0; jp < 16; ++jp) {
            unsigned u = uw[jp];
            #pragma unroll
            for (int h = 0; h < 2; ++h) {
                int k = 2*jp + h;
                float hval = bf2f(h ? (u >> 16) : (u & 0xffffu));
                float x  = fmaf(C2[k],    hval, C2[32+k]);
                float tg = fmaf(C2[64+k], hval, C2[96+k]);
                float gate = __builtin_amdgcn_rcpf(1.f + __expf(-tg));
                float al = a2[k];
                acc = fmaf(x * fmaf(gate, 1.f - al, al), Wf[k], acc);
            }
        }
        score = (mask[g] > 0) ? acc : -1e9f;
    }
    float m = wmax(score);
    if ((t & 63) == 0) rmax[t >> 6] = m;
    __syncthreads();
    m = fmaxf(fmaxf(rmax[0],rmax[1]), fmaxf(rmax[2],rmax[3]));
    float ee = __expf(score - m);
    float zs = wsum(ee);
    if ((t & 63) == 0) rsum[t >> 6] = zs;
    __syncthreads();
    float Z = rsum[0]+rsum[1]+rsum[2]+rsum[3];
    wgt[t] = ee * __builtin_amdgcn_rcpf(Z);
    __syncthreads();
    const int e = t & 63, p = t >> 6;
    const float* fb = facts + (size_t)b*(NS*NE) + e;
    float acc2 = 0.f;
    for (int s = p; s < NS; s += 4) {
        acc2 = fmaf(wgt[s], fb[(size_t)s*64], acc2);
    }
    par[p][e] = acc2;
    __syncthreads();
    if (t < 64) out[(size_t)b*64 + t] = par[0][t]+par[1][t]+par[2][t]+par[3][t];
}

extern "C" void kernel_launch(void* const* d_in, const int* in_sizes, int n_in,
                              void* d_out, int out_size, void* d_ws, size_t ws_size,
                              hipStream_t stream) {
    const float* query = (const float*)d_in[0];
    const float* facts = (const float*)d_in[1];
    const int*   mask  = (const int*)d_in[2];
    const float* W1  = (const float*)d_in[3];
    const float* b1  = (const float*)d_in[4];
    const float* g1  = (const float*)d_in[5];
    const float* be1 = (const float*)d_in[6];
    const float* dg1 = (const float*)d_in[7];
    const float* db1 = (const float*)d_in[8];
    const float* a1  = (const float*)d_in[9];
    const float* W2  = (const float*)d_in[10];
    const float* b2  = (const float*)d_in[11];
    const float* g2  = (const float*)d_in[12];
    const float* be2 = (const float*)d_in[13];
    const float* dg2 = (const float*)d_in[14];
    const float* db2 = (const float*)d_in[15];
    const float* a2  = (const float*)d_in[16];
    const float* Wf  = (const float*)d_in[17];
    const float* bff = (const float*)d_in[18];
    float* out = (float*)d_out;

    float* ws = (float*)d_ws;
    float* gsum1 = ws + 0;     // 64
    float* gsq1  = ws + 64;    // 64
    float* gsum2 = ws + 128;   // 32
    float* gsq2  = ws + 160;   // 32
    float* C1    = ws + 256;   // 256 (A,B,G,H x64)
    float* C2    = ws + 512;   // 128 (A,B,G,H x32)
    float* W2T   = ws + 640;   // 2048
    unsigned* h1p = (unsigned*)(ws + 4096);          // NROWS * 32 u32 = 105 MB
    unsigned* h2p = h1p + (size_t)NROWS*32;          // NROWS * 16 u32 = 52 MB
    (void)ws_size; (void)in_sizes; (void)n_in; (void)out_size;

    k_prep<<<1, 256, 0, stream>>>(W2, ws, W2T);
    k_pass1<<<NB, 256, 0, stream>>>(query, facts, W1, b1, gsum1, gsq1, h1p);
    k_fin<<<1, 64, 0, stream>>>(gsum1, gsq1, g1, be1, dg1, db1, C1, 64);
    k_pass2<<<NROWS/256, 256, 0, stream>>>(h1p, C1, a1, W2T, b2, h2p);
    k_stats2<<<2048, 256, 0, stream>>>(h2p, gsum2, gsq2);
    k_fin<<<1, 32, 0, stream>>>(gsum2, gsq2, g2, be2, dg2, db2, C2, 32);
    k_pass3<<<NB, 256, 0, stream>>>(h2p, C2, a2, Wf, bff, mask, facts, out);
}

// Round 4
// 317.226 us; speedup vs baseline: 2.6563x; 1.3515x over previous
//
#include <hip/hip_runtime.h>
#include <hip/hip_bf16.h>

#define NB 4096
#define NS 200
#define NE 64
#define NROWS (NB*NS)   // 819200

typedef __attribute__((ext_vector_type(8))) short bf16x8;
typedef __attribute__((ext_vector_type(4))) float f32x4;

__device__ __forceinline__ float bf2f(unsigned v) {
    return __uint_as_float(v << 16);
}
__device__ __forceinline__ unsigned f2bf(float x) {
    unsigned u = __float_as_uint(x);
    u = u + 0x7fffu + ((u >> 16) & 1u);
    return u >> 16;
}
__device__ __forceinline__ float wsum(float v) {
    #pragma unroll
    for (int m = 32; m; m >>= 1) v += __shfl_xor(v, m, 64);
    return v;
}
__device__ __forceinline__ float wmax(float v) {
    #pragma unroll
    for (int m = 32; m; m >>= 1) v = fmaxf(v, __shfl_xor(v, m, 64));
    return v;
}

// ------- prep: zero stats accumulators, W2^T -> bf16 hi/lo tables ------------
__global__ __launch_bounds__(256) void k_prep(const float* __restrict__ W2,
                                              float* __restrict__ stats,
                                              unsigned short* __restrict__ W2h,
                                              unsigned short* __restrict__ W2l) {
    int t = threadIdx.x;
    if (t < 192) stats[t] = 0.f;
    #pragma unroll
    for (int r = 0; r < 8; ++r) {
        int idx = r*256 + t;
        int k = idx >> 5, j = idx & 31;
        float v = W2[idx];
        unsigned hb = f2bf(v);
        W2h[j*64 + k] = (unsigned short)hb;
        W2l[j*64 + k] = (unsigned short)f2bf(v - bf2f(hb));
    }
}

// ---------------- pass1 (MFMA): h1 = facts @ M[b] + qW[b], col stats ---------
__global__ __launch_bounds__(256) void k_pass1(const float* __restrict__ query,
        const float* __restrict__ facts,
        const float* __restrict__ W1,
        const float* __restrict__ b1,
        float* __restrict__ gsum, float* __restrict__ gsq,
        unsigned* __restrict__ h1p) {
    __shared__ float qs[64];
    __shared__ float red[4][64];
    __shared__ float qw[64];
    __shared__ unsigned Mt[64*36];     // Mt[j]: 32 data words (64 bf16, e-major) + 4 pad
    __shared__ unsigned h1s[208*32];   // [row][word], word bank-swizzled by ((row>>2)&3)<<3
    __shared__ float sred[4][128];

    const int b = blockIdx.x;
    const int t = threadIdx.x;
    const int l = t & 63, w = t >> 6;

    if (t < 64) qs[t] = query[(size_t)b*64 + t];
    __syncthreads();

    // ---- build M (bf16, transposed: Mt[j][e]) + qW partials ----
    {
        const int j = t & 63;
        const int e0 = (t >> 6) * 16;
        float qp = 0.f;
        #pragma unroll
        for (int ee = 0; ee < 16; ee += 2) {
            const int e = e0 + ee;
            float w0a = W1[(size_t)(e)*64 + j];
            float w1a = W1[(size_t)(64+e)*64 + j];
            float w2a = W1[(size_t)(128+e)*64 + j];
            float w3a = W1[(size_t)(192+e)*64 + j];
            float qe0 = qs[e];
            float m0 = (w1a - w2a) + qe0 * w3a;
            qp = fmaf(qe0, w0a + w2a, qp);
            float w0b = W1[(size_t)(e+1)*64 + j];
            float w1b = W1[(size_t)(64+e+1)*64 + j];
            float w2b = W1[(size_t)(128+e+1)*64 + j];
            float w3b = W1[(size_t)(192+e+1)*64 + j];
            float qe1 = qs[e+1];
            float m1 = (w1b - w2b) + qe1 * w3b;
            qp = fmaf(qe1, w0b + w2b, qp);
            Mt[j*36 + ((e0+ee)>>1)] = f2bf(m0) | (f2bf(m1) << 16);
        }
        red[t>>6][j] = qp;
    }
    __syncthreads();
    if (t < 64) qw[t] = b1[t] + red[0][t]+red[1][t]+red[2][t]+red[3][t];
    __syncthreads();

    // ---- B fragments: Bf[colgroup][kstep], lane: col=l&15, k=ks*32+8*(l>>4)+i ----
    bf16x8 Bf[4][2];
    #pragma unroll
    for (int cg = 0; cg < 4; ++cg) {
        #pragma unroll
        for (int ks = 0; ks < 2; ++ks) {
            int j = cg*16 + (l & 15);
            int e0 = ks*32 + 8*(l >> 4);
            Bf[cg][ks] = *(const bf16x8*)&Mt[j*36 + (e0 >> 1)];
        }
    }
    float qwr[4];
    #pragma unroll
    for (int cg = 0; cg < 4; ++cg) qwr[cg] = qw[cg*16 + (l & 15)];

    float s_acc[4] = {0,0,0,0}, q_acc[4] = {0,0,0,0};
    const float* fb = facts + (size_t)b*(NS*NE);

    for (int rt = w; rt < 13; rt += 4) {
        const int row = rt*16 + (l & 15);
        const int k0 = 8 * (l >> 4);
        float a0[8] = {0,0,0,0,0,0,0,0};
        float a1[8] = {0,0,0,0,0,0,0,0};
        if (row < 200) {
            const float* p = fb + (size_t)row*64 + k0;
            *(float4*)&a0[0] = *(const float4*)(p);
            *(float4*)&a0[4] = *(const float4*)(p + 4);
            *(float4*)&a1[0] = *(const float4*)(p + 32);
            *(float4*)&a1[4] = *(const float4*)(p + 36);
        }
        // split each float into hi(bf16) + lo(bf16 of residual)
        bf16x8 Ah0, Al0, Ah1, Al1;
        #pragma unroll
        for (int i = 0; i < 8; ++i) {
            unsigned hb = f2bf(a0[i]);
            Ah0[i] = (short)hb;
            Al0[i] = (short)f2bf(a0[i] - bf2f(hb));
            unsigned hb1 = f2bf(a1[i]);
            Ah1[i] = (short)hb1;
            Al1[i] = (short)f2bf(a1[i] - bf2f(hb1));
        }
        f32x4 cacc[4];
        #pragma unroll
        for (int cg = 0; cg < 4; ++cg) cacc[cg] = (f32x4){0.f,0.f,0.f,0.f};
        #pragma unroll
        for (int cg = 0; cg < 4; ++cg) {
            cacc[cg] = __builtin_amdgcn_mfma_f32_16x16x32_bf16(Ah0, Bf[cg][0], cacc[cg], 0,0,0);
            cacc[cg] = __builtin_amdgcn_mfma_f32_16x16x32_bf16(Ah1, Bf[cg][1], cacc[cg], 0,0,0);
            cacc[cg] = __builtin_amdgcn_mfma_f32_16x16x32_bf16(Al0, Bf[cg][0], cacc[cg], 0,0,0);
            cacc[cg] = __builtin_amdgcn_mfma_f32_16x16x32_bf16(Al1, Bf[cg][1], cacc[cg], 0,0,0);
        }
        // epilogue: +qW, stats, LDS h1 write. C layout: col=l&15(+16cg), row=4*(l>>4)+reg
        #pragma unroll
        for (int cg = 0; cg < 4; ++cg) {
            const int c_col = cg*16 + (l & 15);
            #pragma unroll
            for (int r = 0; r < 4; ++r) {
                const int rr = rt*16 + 4*(l >> 4) + r;
                float v = cacc[cg][r] + qwr[cg];
                if (rr < 200) {
                    s_acc[cg] += v;
                    q_acc[cg] = fmaf(v, v, q_acc[cg]);
                    const int g_ = (rr >> 2) & 3;
                    const int wrd = (c_col >> 1) ^ (g_ << 3);
                    ((unsigned short*)h1s)[rr*64 + wrd*2 + (c_col & 1)] =
                        (unsigned short)f2bf(v);
                }
            }
        }
    }

    // wave-level column reduce (combine the 4 lane-groups), stage to LDS
    #pragma unroll
    for (int cg = 0; cg < 4; ++cg) {
        s_acc[cg] += __shfl_xor(s_acc[cg], 16, 64);
        s_acc[cg] += __shfl_xor(s_acc[cg], 32, 64);
        q_acc[cg] += __shfl_xor(q_acc[cg], 16, 64);
        q_acc[cg] += __shfl_xor(q_acc[cg], 32, 64);
    }
    if ((l >> 4) == 0) {
        #pragma unroll
        for (int cg = 0; cg < 4; ++cg) {
            sred[w][cg*16 + l] = s_acc[cg];
            sred[w][64 + cg*16 + l] = q_acc[cg];
        }
    }
    __syncthreads();

    if (t < 128) {
        float v = sred[0][t]+sred[1][t]+sred[2][t]+sred[3][t];
        if (t < 64) atomicAdd(gsum + t, v);
        else        atomicAdd(gsq + (t - 64), v);
    }

    // coalesced h1 store: [row][32 words], unswizzle
    #pragma unroll
    for (int it = 0; it < 25; ++it) {
        const int idx = it*256 + t;
        const int row = idx >> 5, wd = idx & 31;
        const int sw = ((row >> 2) & 3) << 3;
        h1p[((size_t)b*200 + row)*32 + wd] = h1s[row*32 + (wd ^ sw)];
    }
}

// -------- finalize: fold BN+Dice into 4 per-channel constants A,B,G,H --------
__global__ __launch_bounds__(64) void k_fin(const float* __restrict__ gsum,
        const float* __restrict__ gsq,
        const float* __restrict__ gam, const float* __restrict__ bet,
        const float* __restrict__ dg, const float* __restrict__ db,
        float* __restrict__ C, int n) {
    int j = threadIdx.x;
    if (j >= n) return;
    const float Ninv = 1.0f / (float)NROWS;
    float m = gsum[j] * Ninv;
    float v = fmaxf(gsq[j]*Ninv - m*m, 0.f);
    float rstd = rsqrtf(v + 1e-5f);
    float A = gam[j] * rstd;
    float Bc = bet[j] - A*m;
    float vard = A*A*v;                   // = gamma^2 * v/(v+eps)
    float rstdd = rsqrtf(vard + 1e-8f);
    float G = dg[j] * rstdd * A;
    float H = db[j] - G*m;
    C[j] = A; C[n+j] = Bc; C[2*n+j] = G; C[3*n+j] = H;
}

// --- pass2 (MFMA): h1 -> dice1 -> h2 = h1d @ W2 + b2 (bf16), fused stats2 ----
// block = 256 threads = 4 waves; block covers 256 rows; wave w: 4 tiles of 16.
__global__ __launch_bounds__(256) void k_pass2(const unsigned short* __restrict__ h1u,
        const float* __restrict__ C1, const float* __restrict__ a1,
        const unsigned short* __restrict__ W2h, const unsigned short* __restrict__ W2l,
        const float* __restrict__ b2,
        unsigned short* __restrict__ h2u,
        float* __restrict__ gsum2, float* __restrict__ gsq2) {
    __shared__ float Cs[320];
    __shared__ float sred[4][64];
    const int t = threadIdx.x;
    const int l = t & 63, w = t >> 6;
    if (t < 256) Cs[t] = C1[t];
    if (t < 64)  Cs[256 + t] = a1[t];
    __syncthreads();

    // B fragments: col = cg*16 + (l&15), k0 = ks*32 + 8*(l>>4)
    bf16x8 Bh[2][2], Bl[2][2];
    #pragma unroll
    for (int cg = 0; cg < 2; ++cg) {
        const int col = cg*16 + (l & 15);
        #pragma unroll
        for (int ks = 0; ks < 2; ++ks) {
            const int k0 = ks*32 + 8*(l >> 4);
            Bh[cg][ks] = *(const bf16x8*)&W2h[col*64 + k0];
            Bl[cg][ks] = *(const bf16x8*)&W2l[col*64 + k0];
        }
    }
    float b2r[2];
    #pragma unroll
    for (int cg = 0; cg < 2; ++cg) b2r[cg] = b2[cg*16 + (l & 15)];

    float s_acc[2] = {0,0}, q_acc[2] = {0,0};
    const int rbase0 = blockIdx.x*256 + w*64;

    for (int tt = 0; tt < 4; ++tt) {
        const int rbase = rbase0 + tt*16;
        const int arow = rbase + (l & 15);
        bf16x8 Ah[2], Al[2];
        #pragma unroll
        for (int ks = 0; ks < 2; ++ks) {
            const int k0 = ks*32 + 8*(l >> 4);
            bf16x8 hv = *(const bf16x8*)&h1u[(size_t)arow*64 + k0];
            #pragma unroll
            for (int i = 0; i < 8; ++i) {
                const int kc = k0 + i;
                float h = bf2f((unsigned short)hv[i]);
                float x  = fmaf(Cs[kc],     h, Cs[64+kc]);
                float tg = fmaf(Cs[128+kc], h, Cs[192+kc]);
                float gate = __builtin_amdgcn_rcpf(1.f + __expf(-tg));
                float al = Cs[256+kc];
                float hd = x * fmaf(gate, 1.f - al, al);
                unsigned hb = f2bf(hd);
                Ah[ks][i] = (short)hb;
                Al[ks][i] = (short)f2bf(hd - bf2f(hb));
            }
        }
        f32x4 cacc[2];
        #pragma unroll
        for (int cg = 0; cg < 2; ++cg) {
            cacc[cg] = (f32x4){0.f,0.f,0.f,0.f};
            cacc[cg] = __builtin_amdgcn_mfma_f32_16x16x32_bf16(Ah[0], Bh[cg][0], cacc[cg], 0,0,0);
            cacc[cg] = __builtin_amdgcn_mfma_f32_16x16x32_bf16(Ah[1], Bh[cg][1], cacc[cg], 0,0,0);
            cacc[cg] = __builtin_amdgcn_mfma_f32_16x16x32_bf16(Al[0], Bh[cg][0], cacc[cg], 0,0,0);
            cacc[cg] = __builtin_amdgcn_mfma_f32_16x16x32_bf16(Al[1], Bh[cg][1], cacc[cg], 0,0,0);
            cacc[cg] = __builtin_amdgcn_mfma_f32_16x16x32_bf16(Ah[0], Bl[cg][0], cacc[cg], 0,0,0);
            cacc[cg] = __builtin_amdgcn_mfma_f32_16x16x32_bf16(Ah[1], Bl[cg][1], cacc[cg], 0,0,0);
        }
        // epilogue: + b2, stats, bf16 store. C layout: col=l&15(+16cg), row=4*(l>>4)+r
        #pragma unroll
        for (int cg = 0; cg < 2; ++cg) {
            const int col = cg*16 + (l & 15);
            #pragma unroll
            for (int r = 0; r < 4; ++r) {
                const int rr = rbase + 4*(l >> 4) + r;
                float v = cacc[cg][r] + b2r[cg];
                s_acc[cg] += v;
                q_acc[cg] = fmaf(v, v, q_acc[cg]);
                h2u[(size_t)rr*32 + col] = (unsigned short)f2bf(v);
            }
        }
    }

    // stats reduce: combine 4 row-groups -> lanes 0-15 hold per-col totals
    #pragma unroll
    for (int cg = 0; cg < 2; ++cg) {
        s_acc[cg] += __shfl_xor(s_acc[cg], 16, 64);
        s_acc[cg] += __shfl_xor(s_acc[cg], 32, 64);
        q_acc[cg] += __shfl_xor(q_acc[cg], 16, 64);
        q_acc[cg] += __shfl_xor(q_acc[cg], 32, 64);
    }
    if ((l >> 4) == 0) {
        #pragma unroll
        for (int cg = 0; cg < 2; ++cg) {
            sred[w][cg*16 + l] = s_acc[cg];
            sred[w][32 + cg*16 + l] = q_acc[cg];
        }
    }
    __syncthreads();
    if (t < 64) {
        float v = sred[0][t]+sred[1][t]+sred[2][t]+sred[3][t];
        if (t < 32) atomicAdd(gsum2 + t, v);
        else        atomicAdd(gsq2 + (t - 32), v);
    }
}

// ------- pass3: dice2 + scores + mask + softmax + weighted facts sum ---------
__global__ __launch_bounds__(256) void k_pass3(const unsigned* __restrict__ h2p,
        const float* __restrict__ C2, const float* __restrict__ a2,
        const float* __restrict__ Wf, const float* __restrict__ bfp,
        const int* __restrict__ mask, const float* __restrict__ facts,
        float* __restrict__ out) {
    __shared__ float rmax[4], rsum[4], wgt[256], par[4][64];
    const int b = blockIdx.x, t = threadIdx.x;
    float score = -1e30f;
    if (t < NS) {
        size_t g = (size_t)b*NS + t;
        const uint4* hv = (const uint4*)(h2p + g*16);
        uint4 U0 = hv[0], U1 = hv[1], U2 = hv[2], U3 = hv[3];
        unsigned uw[16] = {U0.x,U0.y,U0.z,U0.w, U1.x,U1.y,U1.z,U1.w,
                           U2.x,U2.y,U2.z,U2.w, U3.x,U3.y,U3.z,U3.w};
        float acc = bfp[0];
        #pragma unroll
        for (int jp = 0; jp < 16; ++jp) {
            unsigned u = uw[jp];
            #pragma unroll
            for (int h = 0; h < 2; ++h) {
                int k = 2*jp + h;
                float hval = bf2f(h ? (u >> 16) : (u & 0xffffu));
                float x  = fmaf(C2[k],    hval, C2[32+k]);
                float tg = fmaf(C2[64+k], hval, C2[96+k]);
                float gate = __builtin_amdgcn_rcpf(1.f + __expf(-tg));
                float al = a2[k];
                acc = fmaf(x * fmaf(gate, 1.f - al, al), Wf[k], acc);
            }
        }
        score = (mask[g] > 0) ? acc : -1e9f;
    }
    float m = wmax(score);
    if ((t & 63) == 0) rmax[t >> 6] = m;
    __syncthreads();
    m = fmaxf(fmaxf(rmax[0],rmax[1]), fmaxf(rmax[2],rmax[3]));
    float ee = __expf(score - m);
    float zs = wsum(ee);
    if ((t & 63) == 0) rsum[t >> 6] = zs;
    __syncthreads();
    float Z = rsum[0]+rsum[1]+rsum[2]+rsum[3];
    wgt[t] = ee * __builtin_amdgcn_rcpf(Z);
    __syncthreads();
    const int e = t & 63, p = t >> 6;
    const float* fb = facts + (size_t)b*(NS*NE) + e;
    float acc2 = 0.f;
    for (int s = p; s < NS; s += 4) {
        acc2 = fmaf(wgt[s], fb[(size_t)s*64], acc2);
    }
    par[p][e] = acc2;
    __syncthreads();
    if (t < 64) out[(size_t)b*64 + t] = par[0][t]+par[1][t]+par[2][t]+par[3][t];
}

extern "C" void kernel_launch(void* const* d_in, const int* in_sizes, int n_in,
                              void* d_out, int out_size, void* d_ws, size_t ws_size,
                              hipStream_t stream) {
    const float* query = (const float*)d_in[0];
    const float* facts = (const float*)d_in[1];
    const int*   mask  = (const int*)d_in[2];
    const float* W1  = (const float*)d_in[3];
    const float* b1  = (const float*)d_in[4];
    const float* g1  = (const float*)d_in[5];
    const float* be1 = (const float*)d_in[6];
    const float* dg1 = (const float*)d_in[7];
    const float* db1 = (const float*)d_in[8];
    const float* a1  = (const float*)d_in[9];
    const float* W2  = (const float*)d_in[10];
    const float* b2  = (const float*)d_in[11];
    const float* g2  = (const float*)d_in[12];
    const float* be2 = (const float*)d_in[13];
    const float* dg2 = (const float*)d_in[14];
    const float* db2 = (const float*)d_in[15];
    const float* a2  = (const float*)d_in[16];
    const float* Wf  = (const float*)d_in[17];
    const float* bff = (const float*)d_in[18];
    float* out = (float*)d_out;

    float* ws = (float*)d_ws;
    float* gsum1 = ws + 0;     // 64
    float* gsq1  = ws + 64;    // 64
    float* gsum2 = ws + 128;   // 32
    float* gsq2  = ws + 160;   // 32
    float* C1    = ws + 256;   // 256 (A,B,G,H x64)
    float* C2    = ws + 512;   // 128 (A,B,G,H x32)
    unsigned short* W2h = (unsigned short*)(ws + 1024);  // 2048 u16 = ws[1024..2048)
    unsigned short* W2l = (unsigned short*)(ws + 2048);  // 2048 u16 = ws[2048..3072)
    unsigned* h1p = (unsigned*)(ws + 4096);          // NROWS * 32 u32 = 105 MB
    unsigned* h2p = h1p + (size_t)NROWS*32;          // NROWS * 16 u32 = 52 MB
    (void)ws_size; (void)in_sizes; (void)n_in; (void)out_size;

    k_prep<<<1, 256, 0, stream>>>(W2, ws, W2h, W2l);
    k_pass1<<<NB, 256, 0, stream>>>(query, facts, W1, b1, gsum1, gsq1, h1p);
    k_fin<<<1, 64, 0, stream>>>(gsum1, gsq1, g1, be1, dg1, db1, C1, 64);
    k_pass2<<<NROWS/256, 256, 0, stream>>>((const unsigned short*)h1p, C1, a1,
                                           W2h, W2l, b2,
                                           (unsigned short*)h2p, gsum2, gsq2);
    k_fin<<<1, 32, 0, stream>>>(gsum2, gsq2, g2, be2, dg2, db2, C2, 32);
    k_pass3<<<NB, 256, 0, stream>>>(h2p, C2, a2, Wf, bff, mask, facts, out);
}